// Round 11
// baseline (188.783 us; speedup 1.0000x reference)
//
#include <hip/hip_runtime.h>
#include <hip/hip_bf16.h>
#include <cstdint>

#define DIM   1024
#define HEADS 16
#define HDIM  64
#define BATCH 2
#define SEQ   2048
#define ROWS  (BATCH*SEQ)   // 4096
static constexpr float QSCALE = 0.18033688f;        // HDIM^-0.5 * log2(e)

typedef float  f32x4  __attribute__((ext_vector_type(4)));
typedef float  f32x16 __attribute__((ext_vector_type(16)));
typedef float  float4v __attribute__((ext_vector_type(4)));
typedef __bf16 bf16x8 __attribute__((ext_vector_type(8)));
typedef __bf16 bf16x4 __attribute__((ext_vector_type(4)));
typedef __bf16 bf16x2 __attribute__((ext_vector_type(2)));
typedef unsigned u32x4v __attribute__((ext_vector_type(4)));

// async global->LDS, 16B per lane; LDS dest is wave-uniform base + lane*16B
__device__ __forceinline__ void glds16(const __bf16* g, __bf16* l) {
  __builtin_amdgcn_global_load_lds(
      (const __attribute__((address_space(1))) void*)g,
      (__attribute__((address_space(3))) void*)l, 16, 0, 0);
}

// Explicit drain of async global->LDS DMAs before publishing via barrier.
__device__ __forceinline__ void wait_dma0() {
  asm volatile("s_waitcnt vmcnt(0) lgkmcnt(0)" ::: "memory");
}

// ---------------------------------------------------------------------------
// prep: z 0..7 -> fp32->bf16 convert of [x|y]; z == 8 -> W -> Wt[n][k] bf16.
// ---------------------------------------------------------------------------
__global__ __launch_bounds__(256) void prep_kernel(
    const float* __restrict__ x, const float* __restrict__ y,
    const float* __restrict__ Wq, const float* __restrict__ Wk,
    const float* __restrict__ Wv, const float* __restrict__ Wp,
    __bf16* __restrict__ xb, __bf16* __restrict__ yb, __bf16* __restrict__ Wt) {
  const int z = blockIdx.z, t = threadIdx.x;
  const size_t NEL = (size_t)ROWS * DIM;
  if (z < 8) {
    size_t idx = (((size_t)z * 1024 + blockIdx.x) * 256 + t) * 4;
    const float* s; __bf16* d;
    if (idx < NEL) { s = x + idx; d = xb + idx; }
    else           { s = y + (idx - NEL); d = yb + (idx - NEL); }
    const float4v v = *(const float4v*)s;
    bf16x4 o;
    o[0] = (__bf16)v[0]; o[1] = (__bf16)v[1]; o[2] = (__bf16)v[2]; o[3] = (__bf16)v[3];
    *(bf16x4*)d = o;
    return;
  }
  const int w = blockIdx.x >> 8, rem = blockIdx.x & 255;
  const float* W = (w == 0) ? Wq : (w == 1) ? Wk : (w == 2) ? Wv : Wp;
  __bf16* dst = Wt + (size_t)w * DIM * DIM;
  const int n0 = (rem & 15) * 64, k0 = (rem >> 4) * 64;
  __shared__ float T[64][65];
  const int col = t & 63, rw = t >> 6;
  #pragma unroll
  for (int p = 0; p < 16; ++p) {
    const int row = p * 4 + rw;
    T[row][col] = W[(size_t)(k0 + row) * DIM + n0 + col];
  }
  __syncthreads();
  #pragma unroll
  for (int p = 0; p < 16; ++p) {
    const int row = p * 4 + rw;
    dst[(size_t)(n0 + row) * DIM + k0 + col] = (__bf16)T[col][row];
  }
}

// ---------------------------------------------------------------------------
// Fused QKV projection v3 (R10-passing): BK=32 -> 32 KB LDS -> 3 blocks/CU,
// tail-free 768 = 3x256. Stage-ahead dbuf + XCD bijective swizzle.
// 64B LDS rows: slot = quad ^ (row&3); staged via pre-swizzled source col.
// z: 0 -> Q = xb@Wq^T * QSCALE, 1 -> K = yb@Wk^T, 2 -> V = yb@Wv^T written
// TRANSPOSED to VT[(b*16+h)*64+d][key] via swizzled in-LDS transpose.
// ---------------------------------------------------------------------------
__global__ __launch_bounds__(256, 3) void proj_kernel(
    const __bf16* __restrict__ xb, const __bf16* __restrict__ yb,
    const __bf16* __restrict__ Wt,
    __bf16* __restrict__ Qb, __bf16* __restrict__ Kb, __bf16* __restrict__ VT) {
  // bijective XCD swizzle: linear id in dispatch order (x fastest) -> role id
  const int lin = blockIdx.x + 8 * (blockIdx.y + 32 * blockIdx.z);
  const int swz = (lin & 7) * 96 + (lin >> 3);       // 96 roles per XCD
  const int bx = swz & 7, by = (swz >> 3) & 31, z = swz >> 8;

  const __bf16* A = (z == 0) ? xb : yb;
  const __bf16* Bt = Wt + (size_t)z * DIM * DIM;

  __shared__ __bf16 S[2][2][128 * 32];   // [buf][A|B]; 32 KB total

  const int t = threadIdx.x, lane = t & 63, wave = t >> 6;
  const int l15 = lane & 15, quad = lane >> 4;
  const int wm = wave & 1, wn = wave >> 1;
  const int rowBase = by * 128, colBase = bx * 128;
  const int srow2 = lane >> 2;                        // 0..15 (row within wave's 16)
  const int scol2 = ((lane & 3) ^ (srow2 & 3)) * 8;   // pre-swizzled source col (elems)

  f32x4 acc[4][4] = {};

  auto stage = [&](int kb, int buf) {
    #pragma unroll
    for (int c = 0; c < 2; ++c) {
      const int row = c * 64 + wave * 16 + srow2;
      glds16(&A [(size_t)(rowBase + row) * DIM + kb + scol2],
             &S[buf][0][c * 2048 + wave * 512]);
      glds16(&Bt[(size_t)(colBase + row) * DIM + kb + scol2],
             &S[buf][1][c * 2048 + wave * 512]);
    }
  };

  stage(0, 0);
  for (int j = 0; j < DIM / 32; ++j) {
    const int buf = j & 1;
    wait_dma0();               // stage(j) landed (compute of j-1 covered it)
    __syncthreads();           // publish buf; all waves done with buf^1
    if (j + 1 < DIM / 32) stage((j + 1) * 32, buf ^ 1);
    const __bf16* As = S[buf][0];
    const __bf16* Bs = S[buf][1];
    bf16x8 a[4], b[4];
    #pragma unroll
    for (int mi = 0; mi < 4; ++mi) {
      const int row = wm * 64 + mi * 16 + l15;
      a[mi] = *(const bf16x8*)&As[row * 32 + (quad ^ (row & 3)) * 8];
    }
    #pragma unroll
    for (int ni = 0; ni < 4; ++ni) {
      const int row = wn * 64 + ni * 16 + l15;
      b[ni] = *(const bf16x8*)&Bs[row * 32 + (quad ^ (row & 3)) * 8];
    }
    #pragma unroll
    for (int mi = 0; mi < 4; ++mi)
      #pragma unroll
      for (int ni = 0; ni < 4; ++ni)
        acc[mi][ni] = __builtin_amdgcn_mfma_f32_16x16x32_bf16(a[mi], b[ni], acc[mi][ni], 0, 0, 0);
  }

  if (z < 2) {
    __bf16* out = (z == 0) ? Qb : Kb;
    const float sc = (z == 0) ? QSCALE : 1.0f;
    #pragma unroll
    for (int mi = 0; mi < 4; ++mi) {
      const int row0 = rowBase + wm * 64 + mi * 16 + quad * 4;
      #pragma unroll
      for (int ni = 0; ni < 4; ++ni) {
        const int col = colBase + wn * 64 + ni * 16 + l15;
        #pragma unroll
        for (int r = 0; r < 4; ++r)
          out[(size_t)(row0 + r) * DIM + col] = (__bf16)(acc[mi][ni][r] * sc);
      }
    }
    return;
  }

  // z == 2: transpose epilogue (verified R8). Ts element (d,k) at
  // d*128 + ((k>>3)^(d&7))*8 + (k&7); rows=keys, cols=d. Ts = all 32 KB of S.
  __syncthreads();
  __bf16* Ts = &S[0][0][0];           // 128x128 bf16 = 32 KB (exactly S)
  #pragma unroll
  for (int mi = 0; mi < 4; ++mi) {
    const int bk3 = wm * 8 + mi * 2 + (quad >> 1);   // key_local >> 3
    #pragma unroll
    for (int ni = 0; ni < 4; ++ni) {
      const int dl = wn * 64 + ni * 16 + l15;        // d_local
      bf16x4 pk;
      #pragma unroll
      for (int r = 0; r < 4; ++r) pk[r] = (__bf16)acc[mi][ni][r];
      *(bf16x4*)&Ts[dl * 128 + (bk3 ^ (dl & 7)) * 8 + (quad & 1) * 4] = pk;
    }
  }
  __syncthreads();
  const int d = t >> 1, khh = t & 1;
  const size_t vrow = (size_t)((rowBase >> 11) * HEADS * HDIM) + colBase + d;
  const int key0g = rowBase & (SEQ - 1);
  #pragma unroll
  for (int j = 0; j < 8; ++j) {
    const int kc = khh * 8 + j;
    const int lc = (kc & 8) | ((kc ^ d) & 7);
    const bf16x8 v = *(const bf16x8*)&Ts[d * 128 + lc * 8];
    *(bf16x8*)&VT[vrow * SEQ + key0g + kc * 8] = v;
  }
}

// ---------------------------------------------------------------------------
// Flash attention v12 = R10-passing v10 + two attn-local changes:
// (1) bh-grouped XCD swizzle (bijective, 512 = 8x64): 4 bh per XCD -> K/V
//     working set 2 MB < 4 MB L2 -> FETCH collapses toward unique data.
// (2) accumulator chain-split: o0/o1/lacc -> A/B halves (F0-terms vs
//     F1-terms, merged in epilogue) -> serial MFMA chains halve.
// Everything else (staging, swizzle, softmax path, ones-MFMA denominator,
// vmcnt(0) drain) byte-identical to R10.
// ---------------------------------------------------------------------------
__global__ __launch_bounds__(256, 2) void attn_kernel(
    const __bf16* __restrict__ Qb, const __bf16* __restrict__ Kb,
    const __bf16* __restrict__ VT, __bf16* __restrict__ Ob) {
  __shared__ __bf16 KV[2][2][64 * 64];   // [buf][K|V][64x64], XOR-swizzled rows

  const int t = threadIdx.x, lane = t & 63, wave = t >> 6;
  const int x = lane & 31, hi = lane >> 5;
  // bh-grouped XCD swizzle: dispatch lin -> role; XCD k owns bh [4k, 4k+4)
  const int lin = blockIdx.x + 16 * blockIdx.y;      // 512 blocks, x fastest
  const int role = (lin & 7) * 64 + (lin >> 3);      // 64 roles per XCD
  const int bh = role >> 4, qblk = role & 15;
  const int b = bh >> 4, h = bh & 15;
  const int qbase = qblk * 128 + wave * 32;
  const int srow = lane >> 3;
  const int scol = ((lane & 7) ^ srow) * 8;

  const __bf16* Kbh = Kb + (size_t)b * SEQ * DIM + h * HDIM;
  const __bf16* Vbh = VT + (size_t)bh * HDIM * SEQ;

  // Q B-frags: col = x = q_local, k = kd*16 + hi*8 + j  (Q pre-scaled by QSCALE)
  bf16x8 qf[4];
  #pragma unroll
  for (int kd = 0; kd < 4; ++kd)
    qf[kd] = *(const bf16x8*)&Qb[(size_t)(b * SEQ + qbase + x) * DIM
                                 + h * HDIM + kd * 16 + hi * 8];

  // chain-split accumulators: A = F0 contributions, B = F1 contributions
  f32x16 o0a = {}, o0b = {}, o1a = {}, o1b = {};
  f32x16 laccA = {}, laccB = {};

  bf16x8 ones8;
  #pragma unroll
  for (int i = 0; i < 8; ++i) ones8[i] = (__bf16)1.0f;

  const int he16 = (hi ^ (x & 7)) << 4;  // swizzle slot byte base
  const int rowb = x * 128;              // LDS row byte offset (key row / d row)

  auto stage = [&](int jb, int buf) {
    #pragma unroll
    for (int i = 0; i < 2; ++i) {
      const int c = wave * 2 + i;
      const int row = c * 8 + srow;
      glds16(&Kbh[(size_t)(jb + row) * DIM + scol], &KV[buf][0][c * 512]);
      glds16(&Vbh[(size_t)row * SEQ + jb + scol], &KV[buf][1][c * 512]);
    }
  };

  stage(0, 0);
  for (int j = 0; j < SEQ / 64; ++j) {
    const int buf = j & 1;
    wait_dma0();               // guarantee this wave's DMAs landed in LDS
    __syncthreads();           // ...before any wave reads the staged tile
    if (j + 1 < SEQ / 64) stage((j + 1) * 64, buf ^ 1);
    const char* Ks = (const char*)KV[buf][0];
    const char* Vs = (const char*)KV[buf][1];

    // QK^T, both 32-key subtiles: sT col=q(x), row=key=crow(r,hi)
    f32x16 sT0 = {}, sT1 = {};
    #pragma unroll
    for (int kd = 0; kd < 4; ++kd) {
      const bf16x8 kf = *(const bf16x8*)(Ks + rowb + (he16 ^ (kd << 5)));
      sT0 = __builtin_amdgcn_mfma_f32_32x32x16_bf16(kf, qf[kd], sT0, 0, 0, 0);
    }
    #pragma unroll
    for (int kd = 0; kd < 4; ++kd) {
      const bf16x8 kf = *(const bf16x8*)(Ks + 4096 + rowb + (he16 ^ (kd << 5)));
      sT1 = __builtin_amdgcn_mfma_f32_32x32x16_bf16(kf, qf[kd], sT1, 0, 0, 0);
    }

    // per subtile: exp2 -> pack -> permlane swap -> rowsum-MFMA + PV
    #pragma unroll
    for (int kt = 0; kt < 2; ++kt) {
      const f32x16 s = kt ? sT1 : sT0;
      unsigned w[8];
      #pragma unroll
      for (int i = 0; i < 8; ++i) {
        const float p0 = __builtin_amdgcn_exp2f(s[2 * i]);
        const float p1 = __builtin_amdgcn_exp2f(s[2 * i + 1]);
        bf16x2 pk; pk[0] = (__bf16)p0; pk[1] = (__bf16)p1;
        w[i] = __builtin_bit_cast(unsigned, pk);
      }
      // F0 = keys [kt*32, kt*32+16): dwords {w0,w1,partner w0,w1} per hi-half
      // F1 = keys [kt*32+16, kt*32+32)
#if __has_builtin(__builtin_amdgcn_permlane32_swap)
      const auto s02 = __builtin_amdgcn_permlane32_swap(w[0], w[2], false, false);
      const auto s13 = __builtin_amdgcn_permlane32_swap(w[1], w[3], false, false);
      const auto s46 = __builtin_amdgcn_permlane32_swap(w[4], w[6], false, false);
      const auto s57 = __builtin_amdgcn_permlane32_swap(w[5], w[7], false, false);
      const u32x4v f0v = {(unsigned)s02[0], (unsigned)s13[0], (unsigned)s02[1], (unsigned)s13[1]};
      const u32x4v f1v = {(unsigned)s46[0], (unsigned)s57[0], (unsigned)s46[1], (unsigned)s57[1]};
#else
      const unsigned q0 = __shfl_xor((int)w[0], 32, 64), q1 = __shfl_xor((int)w[1], 32, 64);
      const unsigned q2 = __shfl_xor((int)w[2], 32, 64), q3 = __shfl_xor((int)w[3], 32, 64);
      const unsigned q4 = __shfl_xor((int)w[4], 32, 64), q5 = __shfl_xor((int)w[5], 32, 64);
      const unsigned q6 = __shfl_xor((int)w[6], 32, 64), q7 = __shfl_xor((int)w[7], 32, 64);
      const u32x4v f0v = {hi ? q2 : w[0], hi ? q3 : w[1], hi ? w[2] : q0, hi ? w[3] : q1};
      const u32x4v f1v = {hi ? q6 : w[4], hi ? q7 : w[5], hi ? w[6] : q4, hi ? w[7] : q5};
#endif
      const bf16x8 F0 = __builtin_bit_cast(bf16x8, f0v);
      const bf16x8 F1 = __builtin_bit_cast(bf16x8, f1v);

      // row sums on the MFMA pipe (chain-split A/B)
      laccA = __builtin_amdgcn_mfma_f32_32x32x16_bf16(F0, ones8, laccA, 0, 0, 0);
      laccB = __builtin_amdgcn_mfma_f32_32x32x16_bf16(F1, ones8, laccB, 0, 0, 0);

      // PV: V B-frag col=d (=dblock*32+x), k=hi*8+j keys; slot group
      // (kt*4 + kfr*2 + hi) ^ (d&7) -> byte he16 ^ (kt<<6) ^ (kfr<<5)
      const int kb0 = kt << 6;
      {
        const bf16x8 va = *(const bf16x8*)(Vs + rowb + (he16 ^ kb0));
        const bf16x8 vb = *(const bf16x8*)(Vs + 4096 + rowb + (he16 ^ kb0));
        o0a = __builtin_amdgcn_mfma_f32_32x32x16_bf16(F0, va, o0a, 0, 0, 0);
        o1a = __builtin_amdgcn_mfma_f32_32x32x16_bf16(F0, vb, o1a, 0, 0, 0);
      }
      {
        const bf16x8 va = *(const bf16x8*)(Vs + rowb + (he16 ^ (kb0 | 32)));
        const bf16x8 vb = *(const bf16x8*)(Vs + 4096 + rowb + (he16 ^ (kb0 | 32)));
        o0b = __builtin_amdgcn_mfma_f32_32x32x16_bf16(F1, va, o0b, 0, 0, 0);
        o1b = __builtin_amdgcn_mfma_f32_32x32x16_bf16(F1, vb, o1b, 0, 0, 0);
      }
    }
  }

  // finish: merge A/B halves; inv = 1/lacc in-lane (rows match o); no shuffles.
  #pragma unroll
  for (int r = 0; r < 16; ++r) {
    const int q = (r & 3) + 8 * (r >> 2) + 4 * hi;
    const float inv = 1.f / (laccA[r] + laccB[r]);
    __bf16* dst = &Ob[(size_t)(b * SEQ + qbase + q) * DIM + h * HDIM + x];
    dst[0]  = (__bf16)((o0a[r] + o0b[r]) * inv);
    dst[32] = (__bf16)((o1a[r] + o1b[r]) * inv);
  }
}

// ---------------------------------------------------------------------------
// Output projection v2 (R10-passing): 64x128 tile, double-buffered
// stage-ahead K-loop + XCD swizzle (512 = 8 x 64). fp32 out + bias.
// ---------------------------------------------------------------------------
__global__ __launch_bounds__(256, 2) void outproj_kernel(
    const __bf16* __restrict__ A, const __bf16* __restrict__ Bt,
    const float* __restrict__ bias, float* __restrict__ out) {
  const int lin = blockIdx.x + 8 * blockIdx.y;
  const int swz = (lin & 7) * 64 + (lin >> 3);       // 64 roles per XCD
  const int bx = swz & 7, by = swz >> 3;

  __shared__ __bf16 S[2][12288];      // per buf: A 64x64 (4096) + B 128x64 (8192)

  const int t = threadIdx.x, lane = t & 63, wave = t >> 6;
  const int l15 = lane & 15, quad = lane >> 4;
  const int wm = wave & 1, wn = wave >> 1;
  const int rowBase = by * 64, colBase = bx * 128;
  const int srow = lane >> 3;
  const int scol = ((lane & 7) ^ srow) * 8;

  f32x4 acc[2][4] = {};

  auto stage = [&](int kb, int buf) {
    #pragma unroll
    for (int i = 0; i < 2; ++i) {
      const int c = wave * 2 + i;
      const int row = c * 8 + srow;
      glds16(&A[(size_t)(rowBase + row) * DIM + kb + scol], &S[buf][c * 512]);
    }
    #pragma unroll
    for (int i = 0; i < 4; ++i) {
      const int c = wave * 4 + i;
      const int row = c * 8 + srow;
      glds16(&Bt[(size_t)(colBase + row) * DIM + kb + scol], &S[buf][4096 + c * 512]);
    }
  };

  stage(0, 0);
  for (int kb = 0; kb < DIM / 64; ++kb) {
    const int buf = kb & 1;
    wait_dma0();
    __syncthreads();
    if (kb + 1 < DIM / 64) stage((kb + 1) * 64, buf ^ 1);
    const __bf16* As = &S[buf][0];
    const __bf16* Bs = &S[buf][4096];
    #pragma unroll
    for (int ks = 0; ks < 2; ++ks) {
      bf16x8 a[2], b[4];
      #pragma unroll
      for (int mi = 0; mi < 2; ++mi) {
        const int row = wm * 32 + mi * 16 + l15;
        a[mi] = *(const bf16x8*)&As[row * 64 + (((ks << 2) | quad) ^ (row & 7)) * 8];
      }
      #pragma unroll
      for (int ni = 0; ni < 4; ++ni) {
        const int row = wn * 64 + ni * 16 + l15;
        b[ni] = *(const bf16x8*)&Bs[row * 64 + (((ks << 2) | quad) ^ (row & 7)) * 8];
      }
      #pragma unroll
      for (int mi = 0; mi < 2; ++mi)
        #pragma unroll
        for (int ni = 0; ni < 4; ++ni)
          acc[mi][ni] = __builtin_amdgcn_mfma_f32_16x16x32_bf16(a[mi], b[ni], acc[mi][ni], 0, 0, 0);
    }
  }

  #pragma unroll
  for (int mi = 0; mi < 2; ++mi) {
    const int row0 = rowBase + wm * 32 + mi * 16 + quad * 4;
    #pragma unroll
    for (int ni = 0; ni < 4; ++ni) {
      const int col = colBase + wn * 64 + ni * 16 + l15;
      const float bb = bias[col];
      #pragma unroll
      for (int r = 0; r < 4; ++r)
        out[(size_t)(row0 + r) * DIM + col] = acc[mi][ni][r] + bb;
    }
  }
}

// ---------------------------------------------------------------------------
// ws layout (bf16, NEL = 4194304): xb yb Wt[4M] Qb Kb VT = 50.3 MB.
// Ob aliases xb (dead after projections).
// ---------------------------------------------------------------------------
extern "C" void kernel_launch(void* const* d_in, const int* in_sizes, int n_in,
                              void* d_out, int out_size, void* d_ws, size_t ws_size,
                              hipStream_t stream) {
  const float* x  = (const float*)d_in[0];
  const float* y  = (const float*)d_in[1];
  const float* Wq = (const float*)d_in[2];
  const float* Wk = (const float*)d_in[3];
  const float* Wv = (const float*)d_in[4];
  const float* Wp = (const float*)d_in[5];
  const float* bp = (const float*)d_in[6];
  float* out = (float*)d_out;

  const size_t NEL = (size_t)ROWS * DIM;
  __bf16* xb = (__bf16*)d_ws;
  __bf16* yb = xb + NEL;
  __bf16* Wt = yb + NEL;            // [4][1024][1024] (q,k,v,p), transposed [n][k]
  __bf16* Qb = Wt + NEL;
  __bf16* Kb = Qb + NEL;
  __bf16* VT = Kb + NEL;
  __bf16* Ob = xb;                  // alias: xb dead after projections

  prep_kernel<<<dim3(1024, 1, 9), 256, 0, stream>>>(x, y, Wq, Wk, Wv, Wp, xb, yb, Wt);
  proj_kernel<<<dim3(DIM / 128, ROWS / 128, 3), 256, 0, stream>>>(xb, yb, Wt, Qb, Kb, VT);
  attn_kernel<<<dim3(SEQ / 128, BATCH * HEADS), 256, 0, stream>>>(Qb, Kb, VT, Ob);
  outproj_kernel<<<dim3(DIM / 128, ROWS / 64), 256, 0, stream>>>(Ob, Wt + 3 * NEL / 4, bp, out);
}

// Round 13
// 186.395 us; speedup vs baseline: 1.0128x; 1.0128x over previous
//
#include <hip/hip_runtime.h>
#include <hip/hip_bf16.h>
#include <cstdint>

#define DIM   1024
#define HEADS 16
#define HDIM  64
#define BATCH 2
#define SEQ   2048
#define ROWS  (BATCH*SEQ)   // 4096
static constexpr float QSCALE = 0.18033688f;        // HDIM^-0.5 * log2(e)

typedef float  f32x4  __attribute__((ext_vector_type(4)));
typedef float  f32x16 __attribute__((ext_vector_type(16)));
typedef float  float4v __attribute__((ext_vector_type(4)));
typedef __bf16 bf16x8 __attribute__((ext_vector_type(8)));
typedef __bf16 bf16x4 __attribute__((ext_vector_type(4)));
typedef __bf16 bf16x2 __attribute__((ext_vector_type(2)));
typedef unsigned u32x4v __attribute__((ext_vector_type(4)));

// async global->LDS, 16B per lane; LDS dest is wave-uniform base + lane*16B
__device__ __forceinline__ void glds16(const __bf16* g, __bf16* l) {
  __builtin_amdgcn_global_load_lds(
      (const __attribute__((address_space(1))) void*)g,
      (__attribute__((address_space(3))) void*)l, 16, 0, 0);
}

// Explicit drain of async global->LDS DMAs before publishing via barrier.
__device__ __forceinline__ void wait_dma0() {
  asm volatile("s_waitcnt vmcnt(0) lgkmcnt(0)" ::: "memory");
}

// ---------------------------------------------------------------------------
// prep: z 0..7 -> fp32->bf16 convert of [x|y]; z == 8 -> W -> Wt[n][k] bf16.
// ---------------------------------------------------------------------------
__global__ __launch_bounds__(256) void prep_kernel(
    const float* __restrict__ x, const float* __restrict__ y,
    const float* __restrict__ Wq, const float* __restrict__ Wk,
    const float* __restrict__ Wv, const float* __restrict__ Wp,
    __bf16* __restrict__ xb, __bf16* __restrict__ yb, __bf16* __restrict__ Wt) {
  const int z = blockIdx.z, t = threadIdx.x;
  const size_t NEL = (size_t)ROWS * DIM;
  if (z < 8) {
    size_t idx = (((size_t)z * 1024 + blockIdx.x) * 256 + t) * 4;
    const float* s; __bf16* d;
    if (idx < NEL) { s = x + idx; d = xb + idx; }
    else           { s = y + (idx - NEL); d = yb + (idx - NEL); }
    const float4v v = *(const float4v*)s;
    bf16x4 o;
    o[0] = (__bf16)v[0]; o[1] = (__bf16)v[1]; o[2] = (__bf16)v[2]; o[3] = (__bf16)v[3];
    *(bf16x4*)d = o;
    return;
  }
  const int w = blockIdx.x >> 8, rem = blockIdx.x & 255;
  const float* W = (w == 0) ? Wq : (w == 1) ? Wk : (w == 2) ? Wv : Wp;
  __bf16* dst = Wt + (size_t)w * DIM * DIM;
  const int n0 = (rem & 15) * 64, k0 = (rem >> 4) * 64;
  __shared__ float T[64][65];
  const int col = t & 63, rw = t >> 6;
  #pragma unroll
  for (int p = 0; p < 16; ++p) {
    const int row = p * 4 + rw;
    T[row][col] = W[(size_t)(k0 + row) * DIM + n0 + col];
  }
  __syncthreads();
  #pragma unroll
  for (int p = 0; p < 16; ++p) {
    const int row = p * 4 + rw;
    dst[(size_t)(n0 + row) * DIM + k0 + col] = (__bf16)T[col][row];
  }
}

// ---------------------------------------------------------------------------
// Fused QKV projection v3 (R10-passing): BK=32 -> 32 KB LDS -> 3 blocks/CU,
// tail-free 768 = 3x256. Stage-ahead dbuf + XCD bijective swizzle.
// 64B LDS rows: slot = quad ^ (row&3); staged via pre-swizzled source col.
// z: 0 -> Q = xb@Wq^T * QSCALE, 1 -> K = yb@Wk^T, 2 -> V = yb@Wv^T written
// TRANSPOSED to VT[(b*16+h)*64+d][key] via swizzled in-LDS transpose.
// ---------------------------------------------------------------------------
__global__ __launch_bounds__(256, 3) void proj_kernel(
    const __bf16* __restrict__ xb, const __bf16* __restrict__ yb,
    const __bf16* __restrict__ Wt,
    __bf16* __restrict__ Qb, __bf16* __restrict__ Kb, __bf16* __restrict__ VT) {
  // bijective XCD swizzle: linear id in dispatch order (x fastest) -> role id
  const int lin = blockIdx.x + 8 * (blockIdx.y + 32 * blockIdx.z);
  const int swz = (lin & 7) * 96 + (lin >> 3);       // 96 roles per XCD
  const int bx = swz & 7, by = (swz >> 3) & 31, z = swz >> 8;

  const __bf16* A = (z == 0) ? xb : yb;
  const __bf16* Bt = Wt + (size_t)z * DIM * DIM;

  __shared__ __bf16 S[2][2][128 * 32];   // [buf][A|B]; 32 KB total

  const int t = threadIdx.x, lane = t & 63, wave = t >> 6;
  const int l15 = lane & 15, quad = lane >> 4;
  const int wm = wave & 1, wn = wave >> 1;
  const int rowBase = by * 128, colBase = bx * 128;
  const int srow2 = lane >> 2;                        // 0..15 (row within wave's 16)
  const int scol2 = ((lane & 3) ^ (srow2 & 3)) * 8;   // pre-swizzled source col (elems)

  f32x4 acc[4][4] = {};

  auto stage = [&](int kb, int buf) {
    #pragma unroll
    for (int c = 0; c < 2; ++c) {
      const int row = c * 64 + wave * 16 + srow2;
      glds16(&A [(size_t)(rowBase + row) * DIM + kb + scol2],
             &S[buf][0][c * 2048 + wave * 512]);
      glds16(&Bt[(size_t)(colBase + row) * DIM + kb + scol2],
             &S[buf][1][c * 2048 + wave * 512]);
    }
  };

  stage(0, 0);
  for (int j = 0; j < DIM / 32; ++j) {
    const int buf = j & 1;
    wait_dma0();               // stage(j) landed (compute of j-1 covered it)
    __syncthreads();           // publish buf; all waves done with buf^1
    if (j + 1 < DIM / 32) stage((j + 1) * 32, buf ^ 1);
    const __bf16* As = S[buf][0];
    const __bf16* Bs = S[buf][1];
    bf16x8 a[4], b[4];
    #pragma unroll
    for (int mi = 0; mi < 4; ++mi) {
      const int row = wm * 64 + mi * 16 + l15;
      a[mi] = *(const bf16x8*)&As[row * 32 + (quad ^ (row & 3)) * 8];
    }
    #pragma unroll
    for (int ni = 0; ni < 4; ++ni) {
      const int row = wn * 64 + ni * 16 + l15;
      b[ni] = *(const bf16x8*)&Bs[row * 32 + (quad ^ (row & 3)) * 8];
    }
    #pragma unroll
    for (int mi = 0; mi < 4; ++mi)
      #pragma unroll
      for (int ni = 0; ni < 4; ++ni)
        acc[mi][ni] = __builtin_amdgcn_mfma_f32_16x16x32_bf16(a[mi], b[ni], acc[mi][ni], 0, 0, 0);
  }

  if (z < 2) {
    __bf16* out = (z == 0) ? Qb : Kb;
    const float sc = (z == 0) ? QSCALE : 1.0f;
    #pragma unroll
    for (int mi = 0; mi < 4; ++mi) {
      const int row0 = rowBase + wm * 64 + mi * 16 + quad * 4;
      #pragma unroll
      for (int ni = 0; ni < 4; ++ni) {
        const int col = colBase + wn * 64 + ni * 16 + l15;
        #pragma unroll
        for (int r = 0; r < 4; ++r)
          out[(size_t)(row0 + r) * DIM + col] = (__bf16)(acc[mi][ni][r] * sc);
      }
    }
    return;
  }

  // z == 2: transpose epilogue (verified R8). Ts element (d,k) at
  // d*128 + ((k>>3)^(d&7))*8 + (k&7); rows=keys, cols=d. Ts = all 32 KB of S.
  __syncthreads();
  __bf16* Ts = &S[0][0][0];           // 128x128 bf16 = 32 KB (exactly S)
  #pragma unroll
  for (int mi = 0; mi < 4; ++mi) {
    const int bk3 = wm * 8 + mi * 2 + (quad >> 1);   // key_local >> 3
    #pragma unroll
    for (int ni = 0; ni < 4; ++ni) {
      const int dl = wn * 64 + ni * 16 + l15;        // d_local
      bf16x4 pk;
      #pragma unroll
      for (int r = 0; r < 4; ++r) pk[r] = (__bf16)acc[mi][ni][r];
      *(bf16x4*)&Ts[dl * 128 + (bk3 ^ (dl & 7)) * 8 + (quad & 1) * 4] = pk;
    }
  }
  __syncthreads();
  const int d = t >> 1, khh = t & 1;
  const size_t vrow = (size_t)((rowBase >> 11) * HEADS * HDIM) + colBase + d;
  const int key0g = rowBase & (SEQ - 1);
  #pragma unroll
  for (int j = 0; j < 8; ++j) {
    const int kc = khh * 8 + j;
    const int lc = (kc & 8) | ((kc ^ d) & 7);
    const bf16x8 v = *(const bf16x8*)&Ts[d * 128 + lc * 8];
    *(bf16x8*)&VT[vrow * SEQ + key0g + kc * 8] = v;
  }
}

// ---------------------------------------------------------------------------
// Flash attention v13 = R11-passing v12 with KVBLK=128 as TWO verified
// 64-key sub-tiles per barrier: LDS layout/swizzle/per-tile compute body are
// byte-identical; only the staging loop stages both halves and the K-loop
// runs the body twice per barrier. Halves the barrier+drain count (32->16)
// and doubles the per-phase window for DMA hiding / wave phase drift.
// bh-grouped XCD swizzle + chain-split accumulators kept from R11.
// ---------------------------------------------------------------------------
__global__ __launch_bounds__(256, 2) void attn_kernel(
    const __bf16* __restrict__ Qb, const __bf16* __restrict__ Kb,
    const __bf16* __restrict__ VT, __bf16* __restrict__ Ob) {
  __shared__ __bf16 KV[2][4][64 * 64];   // [buf][{K0,K1,V0,V1}][64x64]

  const int t = threadIdx.x, lane = t & 63, wave = t >> 6;
  const int x = lane & 31, hi = lane >> 5;
  // bh-grouped XCD swizzle: dispatch lin -> role; XCD k owns bh [4k, 4k+4)
  const int lin = blockIdx.x + 16 * blockIdx.y;      // 512 blocks, x fastest
  const int role = (lin & 7) * 64 + (lin >> 3);      // 64 roles per XCD
  const int bh = role >> 4, qblk = role & 15;
  const int b = bh >> 4, h = bh & 15;
  const int qbase = qblk * 128 + wave * 32;
  const int srow = lane >> 3;
  const int scol = ((lane & 7) ^ srow) * 8;

  const __bf16* Kbh = Kb + (size_t)b * SEQ * DIM + h * HDIM;
  const __bf16* Vbh = VT + (size_t)bh * HDIM * SEQ;

  // Q B-frags: col = x = q_local, k = kd*16 + hi*8 + j  (Q pre-scaled by QSCALE)
  bf16x8 qf[4];
  #pragma unroll
  for (int kd = 0; kd < 4; ++kd)
    qf[kd] = *(const bf16x8*)&Qb[(size_t)(b * SEQ + qbase + x) * DIM
                                 + h * HDIM + kd * 16 + hi * 8];

  // chain-split accumulators: A = F0 contributions, B = F1 contributions
  f32x16 o0a = {}, o0b = {}, o1a = {}, o1b = {};
  f32x16 laccA = {}, laccB = {};

  bf16x8 ones8;
  #pragma unroll
  for (int i = 0; i < 8; ++i) ones8[i] = (__bf16)1.0f;

  const int he16 = (hi ^ (x & 7)) << 4;  // swizzle slot byte base
  const int rowb = x * 128;              // LDS row byte offset (key row / d row)

  // stage 128 keys = two 64-key halves, each with the verified 64-key layout
  auto stage = [&](int jb, int buf) {
    #pragma unroll
    for (int hh = 0; hh < 2; ++hh)
      #pragma unroll
      for (int i = 0; i < 2; ++i) {
        const int c = wave * 2 + i;
        const int row = c * 8 + srow;
        glds16(&Kbh[(size_t)(jb + hh * 64 + row) * DIM + scol], &KV[buf][hh][c * 512]);
        glds16(&Vbh[(size_t)row * SEQ + jb + hh * 64 + scol], &KV[buf][2 + hh][c * 512]);
      }
  };

  stage(0, 0);
  for (int j = 0; j < SEQ / 128; ++j) {
    const int buf = j & 1;
    wait_dma0();               // guarantee this wave's DMAs landed in LDS
    __syncthreads();           // ...before any wave reads the staged tiles
    if (j + 1 < SEQ / 128) stage((j + 1) * 128, buf ^ 1);

    #pragma unroll
    for (int hh = 0; hh < 2; ++hh) {
      const char* Ks = (const char*)KV[buf][hh];
      const char* Vs = (const char*)KV[buf][2 + hh];

      // QK^T, both 32-key subtiles: sT col=q(x), row=key=crow(r,hi)
      f32x16 sT0 = {}, sT1 = {};
      #pragma unroll
      for (int kd = 0; kd < 4; ++kd) {
        const bf16x8 kf = *(const bf16x8*)(Ks + rowb + (he16 ^ (kd << 5)));
        sT0 = __builtin_amdgcn_mfma_f32_32x32x16_bf16(kf, qf[kd], sT0, 0, 0, 0);
      }
      #pragma unroll
      for (int kd = 0; kd < 4; ++kd) {
        const bf16x8 kf = *(const bf16x8*)(Ks + 4096 + rowb + (he16 ^ (kd << 5)));
        sT1 = __builtin_amdgcn_mfma_f32_32x32x16_bf16(kf, qf[kd], sT1, 0, 0, 0);
      }

      // per subtile: exp2 -> pack -> permlane swap -> rowsum-MFMA + PV
      #pragma unroll
      for (int kt = 0; kt < 2; ++kt) {
        const f32x16 s = kt ? sT1 : sT0;
        unsigned w[8];
        #pragma unroll
        for (int i = 0; i < 8; ++i) {
          const float p0 = __builtin_amdgcn_exp2f(s[2 * i]);
          const float p1 = __builtin_amdgcn_exp2f(s[2 * i + 1]);
          bf16x2 pk; pk[0] = (__bf16)p0; pk[1] = (__bf16)p1;
          w[i] = __builtin_bit_cast(unsigned, pk);
        }
        // F0 = keys [kt*32, kt*32+16): dwords {w0,w1,partner w0,w1} per hi-half
        // F1 = keys [kt*32+16, kt*32+32)
#if __has_builtin(__builtin_amdgcn_permlane32_swap)
        const auto s02 = __builtin_amdgcn_permlane32_swap(w[0], w[2], false, false);
        const auto s13 = __builtin_amdgcn_permlane32_swap(w[1], w[3], false, false);
        const auto s46 = __builtin_amdgcn_permlane32_swap(w[4], w[6], false, false);
        const auto s57 = __builtin_amdgcn_permlane32_swap(w[5], w[7], false, false);
        const u32x4v f0v = {(unsigned)s02[0], (unsigned)s13[0], (unsigned)s02[1], (unsigned)s13[1]};
        const u32x4v f1v = {(unsigned)s46[0], (unsigned)s57[0], (unsigned)s46[1], (unsigned)s57[1]};
#else
        const unsigned q0 = __shfl_xor((int)w[0], 32, 64), q1 = __shfl_xor((int)w[1], 32, 64);
        const unsigned q2 = __shfl_xor((int)w[2], 32, 64), q3 = __shfl_xor((int)w[3], 32, 64);
        const unsigned q4 = __shfl_xor((int)w[4], 32, 64), q5 = __shfl_xor((int)w[5], 32, 64);
        const unsigned q6 = __shfl_xor((int)w[6], 32, 64), q7 = __shfl_xor((int)w[7], 32, 64);
        const u32x4v f0v = {hi ? q2 : w[0], hi ? q3 : w[1], hi ? w[2] : q0, hi ? w[3] : q1};
        const u32x4v f1v = {hi ? q6 : w[4], hi ? q7 : w[5], hi ? w[6] : q4, hi ? w[7] : q5};
#endif
        const bf16x8 F0 = __builtin_bit_cast(bf16x8, f0v);
        const bf16x8 F1 = __builtin_bit_cast(bf16x8, f1v);

        // row sums on the MFMA pipe (chain-split A/B)
        laccA = __builtin_amdgcn_mfma_f32_32x32x16_bf16(F0, ones8, laccA, 0, 0, 0);
        laccB = __builtin_amdgcn_mfma_f32_32x32x16_bf16(F1, ones8, laccB, 0, 0, 0);

        // PV: V B-frag col=d (=dblock*32+x), k=hi*8+j keys; slot group
        // (kt*4 + kfr*2 + hi) ^ (d&7) -> byte he16 ^ (kt<<6) ^ (kfr<<5)
        const int kb0 = kt << 6;
        {
          const bf16x8 va = *(const bf16x8*)(Vs + rowb + (he16 ^ kb0));
          const bf16x8 vb = *(const bf16x8*)(Vs + 4096 + rowb + (he16 ^ kb0));
          o0a = __builtin_amdgcn_mfma_f32_32x32x16_bf16(F0, va, o0a, 0, 0, 0);
          o1a = __builtin_amdgcn_mfma_f32_32x32x16_bf16(F0, vb, o1a, 0, 0, 0);
        }
        {
          const bf16x8 va = *(const bf16x8*)(Vs + rowb + (he16 ^ (kb0 | 32)));
          const bf16x8 vb = *(const bf16x8*)(Vs + 4096 + rowb + (he16 ^ (kb0 | 32)));
          o0b = __builtin_amdgcn_mfma_f32_32x32x16_bf16(F1, va, o0b, 0, 0, 0);
          o1b = __builtin_amdgcn_mfma_f32_32x32x16_bf16(F1, vb, o1b, 0, 0, 0);
        }
      }
    }
  }

  // finish: merge A/B halves; inv = 1/lacc in-lane (rows match o); no shuffles.
  #pragma unroll
  for (int r = 0; r < 16; ++r) {
    const int q = (r & 3) + 8 * (r >> 2) + 4 * hi;
    const float inv = 1.f / (laccA[r] + laccB[r]);
    __bf16* dst = &Ob[(size_t)(b * SEQ + qbase + q) * DIM + h * HDIM + x];
    dst[0]  = (__bf16)((o0a[r] + o0b[r]) * inv);
    dst[32] = (__bf16)((o1a[r] + o1b[r]) * inv);
  }
}

// ---------------------------------------------------------------------------
// Output projection v2 (R10-passing): 64x128 tile, double-buffered
// stage-ahead K-loop + XCD swizzle (512 = 8 x 64). fp32 out + bias.
// ---------------------------------------------------------------------------
__global__ __launch_bounds__(256, 2) void outproj_kernel(
    const __bf16* __restrict__ A, const __bf16* __restrict__ Bt,
    const float* __restrict__ bias, float* __restrict__ out) {
  const int lin = blockIdx.x + 8 * blockIdx.y;
  const int swz = (lin & 7) * 64 + (lin >> 3);       // 64 roles per XCD
  const int bx = swz & 7, by = swz >> 3;

  __shared__ __bf16 S[2][12288];      // per buf: A 64x64 (4096) + B 128x64 (8192)

  const int t = threadIdx.x, lane = t & 63, wave = t >> 6;
  const int l15 = lane & 15, quad = lane >> 4;
  const int wm = wave & 1, wn = wave >> 1;
  const int rowBase = by * 64, colBase = bx * 128;
  const int srow = lane >> 3;
  const int scol = ((lane & 7) ^ srow) * 8;

  f32x4 acc[2][4] = {};

  auto stage = [&](int kb, int buf) {
    #pragma unroll
    for (int i = 0; i < 2; ++i) {
      const int c = wave * 2 + i;
      const int row = c * 8 + srow;
      glds16(&A[(size_t)(rowBase + row) * DIM + kb + scol], &S[buf][c * 512]);
    }
    #pragma unroll
    for (int i = 0; i < 4; ++i) {
      const int c = wave * 4 + i;
      const int row = c * 8 + srow;
      glds16(&Bt[(size_t)(colBase + row) * DIM + kb + scol], &S[buf][4096 + c * 512]);
    }
  };

  stage(0, 0);
  for (int kb = 0; kb < DIM / 64; ++kb) {
    const int buf = kb & 1;
    wait_dma0();
    __syncthreads();
    if (kb + 1 < DIM / 64) stage((kb + 1) * 64, buf ^ 1);
    const __bf16* As = &S[buf][0];
    const __bf16* Bs = &S[buf][4096];
    #pragma unroll
    for (int ks = 0; ks < 2; ++ks) {
      bf16x8 a[2], b[4];
      #pragma unroll
      for (int mi = 0; mi < 2; ++mi) {
        const int row = wm * 32 + mi * 16 + l15;
        a[mi] = *(const bf16x8*)&As[row * 64 + (((ks << 2) | quad) ^ (row & 7)) * 8];
      }
      #pragma unroll
      for (int ni = 0; ni < 4; ++ni) {
        const int row = wn * 64 + ni * 16 + l15;
        b[ni] = *(const bf16x8*)&Bs[row * 64 + (((ks << 2) | quad) ^ (row & 7)) * 8];
      }
      #pragma unroll
      for (int mi = 0; mi < 2; ++mi)
        #pragma unroll
        for (int ni = 0; ni < 4; ++ni)
          acc[mi][ni] = __builtin_amdgcn_mfma_f32_16x16x32_bf16(a[mi], b[ni], acc[mi][ni], 0, 0, 0);
    }
  }

  #pragma unroll
  for (int mi = 0; mi < 2; ++mi) {
    const int row0 = rowBase + wm * 32 + mi * 16 + quad * 4;
    #pragma unroll
    for (int ni = 0; ni < 4; ++ni) {
      const int col = colBase + wn * 64 + ni * 16 + l15;
      const float bb = bias[col];
      #pragma unroll
      for (int r = 0; r < 4; ++r)
        out[(size_t)(row0 + r) * DIM + col] = acc[mi][ni][r] + bb;
    }
  }
}

// ---------------------------------------------------------------------------
// ws layout (bf16, NEL = 4194304): xb yb Wt[4M] Qb Kb VT = 50.3 MB.
// Ob aliases xb (dead after projections).
// ---------------------------------------------------------------------------
extern "C" void kernel_launch(void* const* d_in, const int* in_sizes, int n_in,
                              void* d_out, int out_size, void* d_ws, size_t ws_size,
                              hipStream_t stream) {
  const float* x  = (const float*)d_in[0];
  const float* y  = (const float*)d_in[1];
  const float* Wq = (const float*)d_in[2];
  const float* Wk = (const float*)d_in[3];
  const float* Wv = (const float*)d_in[4];
  const float* Wp = (const float*)d_in[5];
  const float* bp = (const float*)d_in[6];
  float* out = (float*)d_out;

  const size_t NEL = (size_t)ROWS * DIM;
  __bf16* xb = (__bf16*)d_ws;
  __bf16* yb = xb + NEL;
  __bf16* Wt = yb + NEL;            // [4][1024][1024] (q,k,v,p), transposed [n][k]
  __bf16* Qb = Wt + NEL;
  __bf16* Kb = Qb + NEL;
  __bf16* VT = Kb + NEL;
  __bf16* Ob = xb;                  // alias: xb dead after projections

  prep_kernel<<<dim3(1024, 1, 9), 256, 0, stream>>>(x, y, Wq, Wk, Wv, Wp, xb, yb, Wt);
  proj_kernel<<<dim3(DIM / 128, ROWS / 128, 3), 256, 0, stream>>>(xb, yb, Wt, Qb, Kb, VT);
  attn_kernel<<<dim3(SEQ / 128, BATCH * HEADS), 256, 0, stream>>>(Qb, Kb, VT, Ob);
  outproj_kernel<<<dim3(DIM / 128, ROWS / 64), 256, 0, stream>>>(Ob, Wt + 3 * NEL / 4, bp, out);
}